// Round 8
// baseline (214.101 us; speedup 1.0000x reference)
//
#include <hip/hip_runtime.h>
#include <hip/hip_bf16.h>

typedef int   i32x4  __attribute__((ext_vector_type(4)));
typedef int   i32x8  __attribute__((ext_vector_type(8)));
typedef float f32x16 __attribute__((ext_vector_type(16)));

__device__ inline void gload_lds16(const void* g, void* l) {
  __builtin_amdgcn_global_load_lds((const __attribute__((address_space(1))) void*)g,
                                   (__attribute__((address_space(3))) void*)l, 16, 0, 0);
}
__device__ inline void gload_lds4(const void* g, void* l) {
  __builtin_amdgcn_global_load_lds((const __attribute__((address_space(1))) void*)g,
                                   (__attribute__((address_space(3))) void*)l, 4, 0, 0);
}
__device__ inline i32x8 pad8(i32x4 v) {
  i32x8 r;
  r[0] = v[0]; r[1] = v[1]; r[2] = v[2]; r[3] = v[3];
  r[4] = 0; r[5] = 0; r[6] = 0; r[7] = 0;
  return r;
}

// ------------- Fused quantization: Hadamard(32) rotate + MXFP4 pack (x and w in one grid) ---
__global__ __launch_bounds__(256) void quant_fused(const float* __restrict__ x,
                                                   const float* __restrict__ wt,
                                                   unsigned char* __restrict__ xq,
                                                   unsigned char* __restrict__ xsc,
                                                   unsigned char* __restrict__ wq,
                                                   unsigned char* __restrict__ wsc,
                                                   const float* __restrict__ ags,
                                                   const float* __restrict__ wgs,
                                                   int xg, int Mrows, int Nrows, int kg) {
  const int first = blockIdx.x * 256;
  const bool isX = first < xg;
  const float* in        = isX ? x   : wt;
  unsigned char* outq    = isX ? xq  : wq;
  unsigned char* outsc   = isX ? xsc : wsc;
  const float gs         = isX ? ags[0] : wgs[0];
  const int rows         = isX ? Mrows : Nrows;
  const int base         = isX ? first : first - xg;
  const int g = base + threadIdx.x;
  const int r = g / kg, j = g - r * kg;

  float t[32];
  const float4* p4 = (const float4*)(in + (size_t)g * 32);
#pragma unroll
  for (int i = 0; i < 8; ++i) {
    float4 v4 = p4[i];
    t[4 * i + 0] = v4.x; t[4 * i + 1] = v4.y;
    t[4 * i + 2] = v4.z; t[4 * i + 3] = v4.w;
  }
#pragma unroll
  for (int s = 0; s < 5; ++s) {
    const int hh = 1 << s;
#pragma unroll
    for (int i = 0; i < 32; ++i) {
      if ((i & hh) == 0) {
        float a = t[i], b = t[i + hh];
        t[i] = a + b;
        t[i + hh] = a - b;
      }
    }
  }

  const float c = 0.17677669529663687f;  // 32^-0.5
  float v[32];
  float am = 0.0f;
#pragma unroll
  for (int i = 0; i < 32; ++i) {
    float vi = (t[i] * c) * gs;
    v[i] = vi;
    am = fmaxf(am, fabsf(vi));
  }

  float a6 = am / 6.0f;
  int ex;
  float mant = frexpf(a6, &ex);
  int e = (mant == 0.5f) ? ex - 1 : ex;  // exact ceil(log2(a6))
  if (e < -127) e = -127;
  if (e > 127) e = 127;
  float inv_s = ldexpf(1.0f, -e);

  unsigned int dw[4] = {0u, 0u, 0u, 0u};
#pragma unroll
  for (int i = 0; i < 32; ++i) {
    float u = v[i] * inv_s;
    float au = fabsf(u);
    int idx = (au > 0.25f) + (au > 0.75f) + (au > 1.25f) + (au > 1.75f)
            + (au > 2.5f) + (au > 3.5f) + (au > 5.0f);
    int code = idx | ((u < 0.0f) ? 8 : 0);
    dw[i >> 3] |= (unsigned)code << ((i & 7) * 4);
  }
  i32x4 packed;
  packed[0] = (int)dw[0]; packed[1] = (int)dw[1];
  packed[2] = (int)dw[2]; packed[3] = (int)dw[3];
  *(i32x4*)(outq + (size_t)r * ((size_t)kg * 16) + (size_t)j * 16) = packed;

  // scale byte: layout [step s][row][8B], byte p = h*4 + kk for block j0 = 2*kk + h
  int s = j >> 3, j0 = j & 7;
  int p = ((j0 & 1) << 2) | (j0 >> 1);
  if (kg == 128) {
    __shared__ unsigned char sl[256];  // [16 steps][2 rows][8B]
    sl[(s << 4) | ((r & 1) << 3) | p] = (unsigned char)(e + 127);
    __syncthreads();
    if (threadIdx.x < 64) {
      int si = threadIdx.x >> 2, wd = threadIdx.x & 3;
      unsigned int vv = *(const unsigned int*)&sl[(si << 4) | (wd << 2)];
      size_t r0 = (size_t)(base / 128);
      *(unsigned int*)(outsc + ((size_t)si * rows + r0) * 8 + (wd << 2)) = vv;
    }
  } else {
    outsc[((size_t)s * rows + r) * 8 + p] = (unsigned char)(e + 127);
  }
}

// ---------------- 128x128 MX-FP4 GEMM: A via LDS (swizzled dbuf), B direct-to-register ----
// 4 waves (2M x 2N), BK=256. R6's proven phase/barrier skeleton; B-fragments loaded
// straight from global (L1/L2-resident under supertiling) into register dbuf BfX/BfY
// (static 2-tile unroll). LDS traffic halved vs R6. Ledger: per tile Bf(t+1)^10 (ph_a)
// + A(t+2)^3 (ph_b) -> vmcnt(13) at tile end drains exactly A(t+1).

#define STAGE_A(kt, h, ldsHalf) do {                                                 \
    const unsigned char* _s = Ab + (size_t)((h)*64 + (w << 3) + (l >> 3)) * KB2      \
                      + (size_t)(kt) * 128 + (size_t)csw * 16;                       \
    gload_lds16(_s, (unsigned char*)(ldsHalf) + (w << 10));                          \
    gload_lds16(_s + ((size_t)KB2 << 5), (unsigned char*)(ldsHalf) + (w << 10) + 4096); \
  } while (0)

#define STAGE_ASC(kt, bf) gload_lds4(AscG + ((size_t)(kt) * M + brow) * 8 + (tid << 2), \
                                     (unsigned char*)&asc[bf][0] + (w << 8))

#define STAGESET_A(kt, bf) do {                                                      \
    STAGE_A(kt, 0, &lds[bf][0][0]); STAGE_A(kt, 1, &lds[bf][1][0]);                  \
    STAGE_ASC(kt, bf);                                                               \
  } while (0)

// B fragments direct from global: per nt, 4 x 16B (chunks 2kk+h) + 4B scale. 10 VMEM.
#define LOADBF(kt, BF, SB) do {                                                      \
    _Pragma("unroll")                                                                \
    for (int nt = 0; nt < 2; ++nt) {                                                 \
      int row = wn * 64 + nt * 32 + (l & 31);                                        \
      const unsigned char* _bp = Bb + (size_t)row * KB2 + (size_t)(kt) * 128 + (h << 4); \
      _Pragma("unroll")                                                              \
      for (int kk = 0; kk < 4; ++kk)                                                 \
        BF[nt][kk] = *(const i32x4*)(_bp + (kk << 5));                               \
      SB[nt] = *(const int*)(BscG + ((size_t)(kt) * N + bcol + row) * 8 + (h << 2)); \
    } } while (0)

#define LOADA(bf, mt) do {                                                           \
    const unsigned char* _ab = &lds[bf][0][0];                                       \
    int row = wm * 64 + (mt) * 32 + (l & 31);                                        \
    int xr = row & 7;                                                                \
    _Pragma("unroll")                                                                \
    for (int kk = 0; kk < 4; ++kk)                                                   \
      af[kk] = *(const i32x4*)(_ab + row * 128 + (((kk * 2 + h) ^ xr) << 4));        \
    sa = *(const int*)((const unsigned char*)&asc[bf][0] + row * 8 + h * 4);         \
  } while (0)

#define MF1(mt, nt, kk, BF, SB)                                                      \
  acc[mt][nt] = __builtin_amdgcn_mfma_scale_f32_32x32x64_f8f6f4(                     \
      pad8(af[kk]), pad8(BF[nt][kk]), acc[mt][nt], 4, 4, kk, sa, kk, SB[nt]);

#define MFMAQ(mt, BF, SB) do {                                                       \
    __builtin_amdgcn_s_setprio(1);                                                   \
    MF1(mt, 0, 0, BF, SB) MF1(mt, 1, 0, BF, SB)                                      \
    MF1(mt, 0, 1, BF, SB) MF1(mt, 1, 1, BF, SB)                                      \
    MF1(mt, 0, 2, BF, SB) MF1(mt, 1, 2, BF, SB)                                      \
    MF1(mt, 0, 3, BF, SB) MF1(mt, 1, 3, BF, SB)                                      \
    __builtin_amdgcn_s_setprio(0);                                                   \
  } while (0)

#define MIDSYNC() do { __builtin_amdgcn_s_barrier();                                 \
    asm volatile("s_waitcnt lgkmcnt(0)" ::: "memory");                               \
    __builtin_amdgcn_sched_barrier(0); } while (0)

#define ENDP() __builtin_amdgcn_s_barrier()
#define VM13() asm volatile("s_waitcnt vmcnt(13)" ::: "memory")

__global__ __launch_bounds__(256, 2) void gemm128_fp4(const unsigned char* __restrict__ Aq,
                                                      const unsigned char* __restrict__ Bq,
                                                      const unsigned char* __restrict__ AscG,
                                                      const unsigned char* __restrict__ BscG,
                                                      float* __restrict__ C,
                                                      const float* __restrict__ bias,
                                                      const float* __restrict__ gsx,
                                                      const float* __restrict__ gsw,
                                                      int M, int N, int K) {
  __shared__ __align__(16) unsigned char lds[2][2][8192];  // [buf][half][64 rows x 128B] A only
  __shared__ __align__(16) unsigned char asc[2][1024];     // [buf][128 rows x 8B]

  const int tid = threadIdx.x;
  const int w = tid >> 6, l = tid & 63;
  const int wm = w >> 1, wn = w & 1;
  const int h = l >> 5;
  const int csw = (l & 7) ^ (l >> 3);  // inverse-swizzled source chunk
  const int KB2 = K >> 1;              // bytes per row

  // T1 + L2 supertiling (proven: FETCH 148->70MB): XCD band + 8x8 supertiles.
  const int ntn = N >> 7;
  const int nwg = gridDim.x;
  int r_t, c_t;
  {
    int bid = blockIdx.x;
    if ((nwg & 7) == 0) {
      int x = bid & 7, o = bid >> 3, cpx = nwg >> 3;
      int rpx = cpx / ntn;
      if ((ntn & 7) == 0 && rpx > 0 && (cpx % ntn) == 0) {
        int g8 = o & 7, rr = (o >> 3) % rpx, ss = o / (8 * rpx);
        r_t = x * rpx + rr;
        c_t = ss * 8 + g8;
      } else {
        int lin = x * cpx + o;
        r_t = lin / ntn; c_t = lin % ntn;
      }
    } else {
      r_t = bid / ntn; c_t = bid % ntn;
    }
  }
  const size_t brow = (size_t)r_t * 128;
  const size_t bcol = (size_t)c_t * 128;

  const unsigned char* Ab = Aq + brow * (size_t)KB2;
  const unsigned char* Bb = Bq + bcol * (size_t)KB2;

  f32x16 acc[2][2];
#pragma unroll
  for (int m = 0; m < 2; ++m)
#pragma unroll
    for (int n = 0; n < 2; ++n)
#pragma unroll
      for (int r = 0; r < 16; ++r) acc[m][n][r] = 0.0f;

  i32x4 af[4];
  int sa;
  i32x4 bfX[2][4], bfY[2][4];
  int sbX[2], sbY[2];

  const int nkt = K / 256;       // 16 (even)

  // Prologue: stage A(0)->buf0, A(1)->buf1 (6 VMEM); load Bf(0)->BfX (10 VMEM).
  // vmcnt(13) drains A(0); [A(1)^3, Bf(0)^10] stay in flight.
  STAGESET_A(0, 0);
  STAGESET_A(1, 1);
  LOADBF(0, bfX, sbX);
  VM13();
  __builtin_amdgcn_s_barrier();

  for (int i = 0; i < nkt / 2; ++i) {
    const int t = 2 * i;
    const int t1 = t + 1;                            // < nkt (nkt even)
    const int t2 = (t + 2 < nkt) ? t + 2 : nkt - 1;  // clamped over-stage: dead data
    const int t3 = (t + 3 < nkt) ? t + 3 : nkt - 1;

    // ---- tile t (even): A from buf0, B from BfX; prefetch Bf(t+1)->BfY ----
    LOADA(0, 0); LOADBF(t1, bfY, sbY);
    MIDSYNC(); MFMAQ(0, bfX, sbX); ENDP();
    LOADA(0, 1);
    MIDSYNC();
    STAGESET_A(t2, 0);          // buf0 readers all issued pre-barrier
    MFMAQ(1, bfX, sbX);
    VM13();                     // drains A(t+1); keeps [Bf(t+1)^10, A(t+2)^3]
    ENDP();

    // ---- tile t+1 (odd): A from buf1, B from BfY; prefetch Bf(t+2)->BfX ----
    LOADA(1, 0); LOADBF(t2, bfX, sbX);
    MIDSYNC(); MFMAQ(0, bfY, sbY); ENDP();
    LOADA(1, 1);
    MIDSYNC();
    STAGESET_A(t3, 1);
    MFMAQ(1, bfY, sbY);
    VM13();                     // drains A(t+2); keeps [Bf(t+2)^10, A(t+3)^3]
    ENDP();
  }

  const float inv = 1.0f / (gsx[0] * gsw[0]);
#pragma unroll
  for (int nt = 0; nt < 2; ++nt) {
    const int col = (int)bcol + wn * 64 + nt * 32 + (l & 31);
    const float bv = bias[col];
#pragma unroll
    for (int mt = 0; mt < 2; ++mt) {
      const size_t rbase = brow + (size_t)(wm * 64 + mt * 32 + 4 * h);
#pragma unroll
      for (int r = 0; r < 16; ++r) {
        const size_t row = rbase + (r & 3) + 8 * (r >> 2);
        C[row * (size_t)N + col] = acc[mt][nt][r] * inv + bv;
      }
    }
  }
}

extern "C" void kernel_launch(void* const* d_in, const int* in_sizes, int n_in,
                              void* d_out, int out_size, void* d_ws, size_t ws_size,
                              hipStream_t stream) {
  const float* x    = (const float*)d_in[0];
  const float* wgt  = (const float*)d_in[1];
  const float* bias = (const float*)d_in[2];
  const float* wgs  = (const float*)d_in[4];
  const float* ags  = (const float*)d_in[5];

  const int N = in_sizes[2];            // 4096
  const int K = in_sizes[1] / N;        // 4096
  const int M = in_sizes[0] / K;        // 8192
  const int kg = K / 32;                // 128

  unsigned char* aq  = (unsigned char*)d_ws;
  unsigned char* bq  = aq + (size_t)M * (K / 2);
  unsigned char* asc = bq + (size_t)N * (K / 2);
  unsigned char* bsc = asc + (size_t)M * kg;

  const int xg = in_sizes[0] / 32;
  const int wg = in_sizes[1] / 32;
  quant_fused<<<dim3((xg + wg) / 256), dim3(256), 0, stream>>>(
      x, wgt, aq, asc, bq, bsc, ags, wgs, xg, M, N, kg);

  dim3 grid((M / 128) * (N / 128));
  gemm128_fp4<<<grid, dim3(256), 0, stream>>>(aq, bq, asc, bsc, (float*)d_out, bias,
                                              ags, wgs, M, N, K);
}

// Round 10
// 166.071 us; speedup vs baseline: 1.2892x; 1.2892x over previous
//
#include <hip/hip_runtime.h>
#include <hip/hip_bf16.h>

typedef int   i32x4  __attribute__((ext_vector_type(4)));
typedef int   i32x8  __attribute__((ext_vector_type(8)));
typedef float f32x16 __attribute__((ext_vector_type(16)));

__device__ inline void gload_lds16(const void* g, void* l) {
  __builtin_amdgcn_global_load_lds((const __attribute__((address_space(1))) void*)g,
                                   (__attribute__((address_space(3))) void*)l, 16, 0, 0);
}
__device__ inline void gload_lds4(const void* g, void* l) {
  __builtin_amdgcn_global_load_lds((const __attribute__((address_space(1))) void*)g,
                                   (__attribute__((address_space(3))) void*)l, 4, 0, 0);
}
__device__ inline i32x8 pad8(i32x4 v) {
  i32x8 r;
  r[0] = v[0]; r[1] = v[1]; r[2] = v[2]; r[3] = v[3];
  r[4] = 0; r[5] = 0; r[6] = 0; r[7] = 0;
  return r;
}

// ------------- Fused quantization: Hadamard(32) rotate + MXFP4 pack (x and w in one grid) ---
__global__ __launch_bounds__(256) void quant_fused(const float* __restrict__ x,
                                                   const float* __restrict__ wt,
                                                   unsigned char* __restrict__ xq,
                                                   unsigned char* __restrict__ xsc,
                                                   unsigned char* __restrict__ wq,
                                                   unsigned char* __restrict__ wsc,
                                                   const float* __restrict__ ags,
                                                   const float* __restrict__ wgs,
                                                   int xg, int Mrows, int Nrows, int kg) {
  const int first = blockIdx.x * 256;
  const bool isX = first < xg;
  const float* in        = isX ? x   : wt;
  unsigned char* outq    = isX ? xq  : wq;
  unsigned char* outsc   = isX ? xsc : wsc;
  const float gs         = isX ? ags[0] : wgs[0];
  const int rows         = isX ? Mrows : Nrows;
  const int base         = isX ? first : first - xg;
  const int g = base + threadIdx.x;
  const int r = g / kg, j = g - r * kg;

  float t[32];
  const float4* p4 = (const float4*)(in + (size_t)g * 32);
#pragma unroll
  for (int i = 0; i < 8; ++i) {
    float4 v4 = p4[i];
    t[4 * i + 0] = v4.x; t[4 * i + 1] = v4.y;
    t[4 * i + 2] = v4.z; t[4 * i + 3] = v4.w;
  }
#pragma unroll
  for (int s = 0; s < 5; ++s) {
    const int hh = 1 << s;
#pragma unroll
    for (int i = 0; i < 32; ++i) {
      if ((i & hh) == 0) {
        float a = t[i], b = t[i + hh];
        t[i] = a + b;
        t[i + hh] = a - b;
      }
    }
  }

  const float c = 0.17677669529663687f;  // 32^-0.5
  float v[32];
  float am = 0.0f;
#pragma unroll
  for (int i = 0; i < 32; ++i) {
    float vi = (t[i] * c) * gs;
    v[i] = vi;
    am = fmaxf(am, fabsf(vi));
  }

  float a6 = am / 6.0f;
  int ex;
  float mant = frexpf(a6, &ex);
  int e = (mant == 0.5f) ? ex - 1 : ex;  // exact ceil(log2(a6))
  if (e < -127) e = -127;
  if (e > 127) e = 127;
  float inv_s = ldexpf(1.0f, -e);

  unsigned int dw[4] = {0u, 0u, 0u, 0u};
#pragma unroll
  for (int i = 0; i < 32; ++i) {
    float u = v[i] * inv_s;
    float au = fabsf(u);
    int idx = (au > 0.25f) + (au > 0.75f) + (au > 1.25f) + (au > 1.75f)
            + (au > 2.5f) + (au > 3.5f) + (au > 5.0f);
    int code = idx | ((u < 0.0f) ? 8 : 0);
    dw[i >> 3] |= (unsigned)code << ((i & 7) * 4);
  }
  i32x4 packed;
  packed[0] = (int)dw[0]; packed[1] = (int)dw[1];
  packed[2] = (int)dw[2]; packed[3] = (int)dw[3];
  *(i32x4*)(outq + (size_t)r * ((size_t)kg * 16) + (size_t)j * 16) = packed;

  // scale byte: layout [superstep s(256k)][row][8B], byte p = h*4 + kk for block j0 = 2*kk + h
  int s = j >> 3, j0 = j & 7;
  int p = ((j0 & 1) << 2) | (j0 >> 1);
  if (kg == 128) {
    __shared__ unsigned char sl[256];  // [16 steps][2 rows][8B]
    sl[(s << 4) | ((r & 1) << 3) | p] = (unsigned char)(e + 127);
    __syncthreads();
    if (threadIdx.x < 64) {
      int si = threadIdx.x >> 2, wd = threadIdx.x & 3;
      unsigned int vv = *(const unsigned int*)&sl[(si << 4) | (wd << 2)];
      size_t r0 = (size_t)(base / 128);
      *(unsigned int*)(outsc + ((size_t)si * rows + r0) * 8 + (wd << 2)) = vv;
    }
  } else {
    outsc[((size_t)s * rows + r) * 8 + p] = (unsigned char)(e + 127);
  }
}

// ---------------- 128x128 MX-FP4 GEMM, BK=128, TRIPLE-buffered LDS (race-free) ----------
// 4 waves (2M x 2N). Tile tau reads buf[tau%3]; tile tau+2 staged into buf[(tau+2)%3],
// whose readers drained >=1 full barrier earlier (no read/write overlap in any phase).
// Scales per 256-k superstep, dbuf, staged during even tiles. opsel = (tau&1)*2 + kk.
// Ledger (per pair): even issues 6 (B,BSC,A,ASC of t+2), odd issues 4 (B,A of t+3);
// VM6 after even (drains tile t+1), VM4 after odd (drains tile t+2 + scales).

#define STAGE2(mb, kt, ldsOp) do {                                                   \
    const unsigned char* _s0 = (mb) + (size_t)((w << 4) + (l >> 2)) * KB2            \
                      + (size_t)(kt) * 64 + (size_t)csw * 16;                        \
    gload_lds16(_s0, (unsigned char*)(ldsOp) + (w << 10));                           \
    gload_lds16(_s0 + ((size_t)KB2 << 6), (unsigned char*)(ldsOp) + 4096 + (w << 10)); \
  } while (0)

#define STAGE_ASC(ss, sbuf) gload_lds4(AscG + ((size_t)(ss) * M + brow) * 8 + (tid << 2), \
                                       (unsigned char*)&asc[sbuf][0] + (w << 8))
#define STAGE_BSC(ss, sbuf) gload_lds4(BscG + ((size_t)(ss) * N + bcol) * 8 + (tid << 2), \
                                       (unsigned char*)&bsc[sbuf][0] + (w << 8))

#define LOADB(bf, ssel) do {                                                         \
    const unsigned char* _bb = &lds[bf][1][0];                                       \
    _Pragma("unroll")                                                                \
    for (int nt = 0; nt < 2; ++nt) {                                                 \
      int row = wn * 64 + nt * 32 + (l & 31);                                        \
      int xr = row & 3;                                                              \
      _Pragma("unroll")                                                              \
      for (int kk = 0; kk < 2; ++kk)                                                 \
        bfr[nt][kk] = *(const i32x4*)(_bb + row * 64 + (((kk * 2 + h) ^ xr) << 4));  \
      sb[nt] = *(const int*)((const unsigned char*)&bsc[ssel][0] + row * 8 + h * 4); \
    } } while (0)

#define LOADA(bf, ssel, mt) do {                                                     \
    const unsigned char* _ab = &lds[bf][0][0];                                       \
    int row = wm * 64 + (mt) * 32 + (l & 31);                                        \
    int xr = row & 3;                                                                \
    _Pragma("unroll")                                                                \
    for (int kk = 0; kk < 2; ++kk)                                                   \
      af[kk] = *(const i32x4*)(_ab + row * 64 + (((kk * 2 + h) ^ xr) << 4));         \
    sa = *(const int*)((const unsigned char*)&asc[ssel][0] + row * 8 + h * 4);       \
  } while (0)

#define MF1(mt, nt, kk, OP)                                                          \
  acc[mt][nt] = __builtin_amdgcn_mfma_scale_f32_32x32x64_f8f6f4(                     \
      pad8(af[kk]), pad8(bfr[nt][kk]), acc[mt][nt], 4, 4, OP, sa, OP, sb[nt]);

#define MFMAQ(mt, P) do {                                                            \
    __builtin_amdgcn_s_setprio(1);                                                   \
    MF1(mt, 0, 0, P) MF1(mt, 1, 0, P)                                                \
    MF1(mt, 0, 1, P + 1) MF1(mt, 1, 1, P + 1)                                        \
    __builtin_amdgcn_s_setprio(0);                                                   \
  } while (0)

#define MIDSYNC() do { __builtin_amdgcn_s_barrier();                                 \
    asm volatile("s_waitcnt lgkmcnt(0)" ::: "memory");                               \
    __builtin_amdgcn_sched_barrier(0); } while (0)

#define ENDP() __builtin_amdgcn_s_barrier()
#define VM6()  asm volatile("s_waitcnt vmcnt(6)" ::: "memory")
#define VM4()  asm volatile("s_waitcnt vmcnt(4)" ::: "memory")

__global__ __launch_bounds__(256, 3) void gemm128_fp4(const unsigned char* __restrict__ Aq,
                                                      const unsigned char* __restrict__ Bq,
                                                      const unsigned char* __restrict__ AscG,
                                                      const unsigned char* __restrict__ BscG,
                                                      float* __restrict__ C,
                                                      const float* __restrict__ bias,
                                                      const float* __restrict__ gsx,
                                                      const float* __restrict__ gsw,
                                                      int M, int N, int K) {
  __shared__ __align__(16) unsigned char lds[3][2][8192];  // [buf][A/B][128 rows x 64B]
  __shared__ __align__(16) unsigned char asc[2][1024];     // [sbuf][128 rows x 8B]
  __shared__ __align__(16) unsigned char bsc[2][1024];

  const int tid = threadIdx.x;
  const int w = tid >> 6, l = tid & 63;
  const int wm = w >> 1, wn = w & 1;
  const int h = l >> 5;
  const int csw = (l & 3) ^ ((l >> 2) & 3);  // inverse-swizzled source chunk
  const int KB2 = K >> 1;                    // bytes per row

  // T1 + L2 supertiling (proven: FETCH 148->70MB): XCD band + 8x8 supertiles.
  const int ntn = N >> 7;
  const int nwg = gridDim.x;
  int r_t, c_t;
  {
    int bid = blockIdx.x;
    if ((nwg & 7) == 0) {
      int x = bid & 7, o = bid >> 3, cpx = nwg >> 3;
      int rpx = cpx / ntn;
      if ((ntn & 7) == 0 && rpx > 0 && (cpx % ntn) == 0) {
        int g8 = o & 7, rr = (o >> 3) % rpx, ss = o / (8 * rpx);
        r_t = x * rpx + rr;
        c_t = ss * 8 + g8;
      } else {
        int lin = x * cpx + o;
        r_t = lin / ntn; c_t = lin % ntn;
      }
    } else {
      r_t = bid / ntn; c_t = bid % ntn;
    }
  }
  const size_t brow = (size_t)r_t * 128;
  const size_t bcol = (size_t)c_t * 128;

  const unsigned char* Ab = Aq + brow * (size_t)KB2;
  const unsigned char* Bb = Bq + bcol * (size_t)KB2;

  f32x16 acc[2][2];
#pragma unroll
  for (int m = 0; m < 2; ++m)
#pragma unroll
    for (int n = 0; n < 2; ++n)
#pragma unroll
      for (int r = 0; r < 16; ++r) acc[m][n][r] = 0.0f;

  i32x4 af[2], bfr[2][2];
  int sa, sb[2];

  const int nkt = K / 128;       // 32 tiles
  const int nss = K / 256;       // 16 scale supersteps

  // Prologue: [B0,BSC0,A0,ASC0] (6) + [B1,A1] (4); VM4 drains tile0 set + scales,
  // keeps [B1,A1] in flight (= steady state entering an even tile).
  STAGE2(Bb, 0, &lds[0][1][0]); STAGE_BSC(0, 0);
  STAGE2(Ab, 0, &lds[0][0][0]); STAGE_ASC(0, 0);
  STAGE2(Bb, 1, &lds[1][1][0]);
  STAGE2(Ab, 1, &lds[1][0][0]);
  VM4();
  __builtin_amdgcn_s_barrier();

  int e = 0, o = 1, n = 2;  // buf of even tile, odd tile, tile+2 (rotates per pair)

  for (int s = 0; s < nkt / 2; ++s) {
    const int t = 2 * s;
    const int t2 = (t + 2 < nkt) ? t + 2 : nkt - 1;  // tail: writes a buffer never read again
    const int t3 = (t + 3 < nkt) ? t + 3 : nkt - 1;
    const int ssel = s & 1;
    const int ss1 = (s + 1 < nss) ? s + 1 : nss - 1;

    // ---- even tile t: reads buf e (staged 2 pairs ago; readers of buf n drained
    //      during pair s-1 odd tile, >=1 full barrier ago) ----
    LOADB(e, ssel); LOADA(e, ssel, 0);
    MIDSYNC();
    STAGE2(Bb, t2, &lds[n][1][0]); STAGE_BSC(ss1, ssel ^ 1);
    MFMAQ(0, 0);
    ENDP();
    LOADA(e, ssel, 1);
    MIDSYNC();
    STAGE2(Ab, t2, &lds[n][0][0]); STAGE_ASC(ss1, ssel ^ 1);
    MFMAQ(1, 0);
    VM6();    // drains B(t+1),A(t+1); keeps t+2 set (6)
    ENDP();

    // ---- odd tile t+1: reads buf o; stages t+3 into buf e (buf e's readers
    //      drained at even ph2, full ENDP between) ----
    LOADB(o, ssel); LOADA(o, ssel, 0);
    MIDSYNC();
    STAGE2(Bb, t3, &lds[e][1][0]);
    MFMAQ(0, 2);
    ENDP();
    LOADA(o, ssel, 1);
    MIDSYNC();
    STAGE2(Ab, t3, &lds[e][0][0]);
    MFMAQ(1, 2);
    VM4();    // drains t+2 set (incl scales); keeps B(t+3),A(t+3)
    ENDP();

    // rotate buffers: (e, o, n) <- (n, e, o)
    int tmp = e; e = n; n = o; o = tmp;
  }

  const float inv = 1.0f / (gsx[0] * gsw[0]);
#pragma unroll
  for (int nt = 0; nt < 2; ++nt) {
    const int col = (int)bcol + wn * 64 + nt * 32 + (l & 31);
    const float bv = bias[col];
#pragma unroll
    for (int mt = 0; mt < 2; ++mt) {
      const size_t rbase = brow + (size_t)(wm * 64 + mt * 32 + 4 * h);
#pragma unroll
      for (int r = 0; r < 16; ++r) {
        const size_t row = rbase + (r & 3) + 8 * (r >> 2);
        C[row * (size_t)N + col] = acc[mt][nt][r] * inv + bv;
      }
    }
  }
}

extern "C" void kernel_launch(void* const* d_in, const int* in_sizes, int n_in,
                              void* d_out, int out_size, void* d_ws, size_t ws_size,
                              hipStream_t stream) {
  const float* x    = (const float*)d_in[0];
  const float* wgt  = (const float*)d_in[1];
  const float* bias = (const float*)d_in[2];
  const float* wgs  = (const float*)d_in[4];
  const float* ags  = (const float*)d_in[5];

  const int N = in_sizes[2];            // 4096
  const int K = in_sizes[1] / N;        // 4096
  const int M = in_sizes[0] / K;        // 8192
  const int kg = K / 32;                // 128

  unsigned char* aq  = (unsigned char*)d_ws;
  unsigned char* bq  = aq + (size_t)M * (K / 2);
  unsigned char* asc = bq + (size_t)N * (K / 2);
  unsigned char* bsc = asc + (size_t)M * kg;

  const int xg = in_sizes[0] / 32;
  const int wg = in_sizes[1] / 32;
  quant_fused<<<dim3((xg + wg) / 256), dim3(256), 0, stream>>>(
      x, wgt, aq, asc, bq, bsc, ags, wgs, xg, M, N, kg);

  dim3 grid((M / 128) * (N / 128));
  gemm128_fp4<<<grid, dim3(256), 0, stream>>>(aq, bq, asc, bsc, (float*)d_out, bias,
                                              ags, wgs, M, N, K);
}

// Round 11
// 148.561 us; speedup vs baseline: 1.4412x; 1.1179x over previous
//
#include <hip/hip_runtime.h>
#include <hip/hip_bf16.h>

typedef int   i32x4  __attribute__((ext_vector_type(4)));
typedef int   i32x8  __attribute__((ext_vector_type(8)));
typedef float f32x16 __attribute__((ext_vector_type(16)));

__device__ inline void gload_lds16(const void* g, void* l) {
  __builtin_amdgcn_global_load_lds((const __attribute__((address_space(1))) void*)g,
                                   (__attribute__((address_space(3))) void*)l, 16, 0, 0);
}
__device__ inline void gload_lds4(const void* g, void* l) {
  __builtin_amdgcn_global_load_lds((const __attribute__((address_space(1))) void*)g,
                                   (__attribute__((address_space(3))) void*)l, 4, 0, 0);
}
__device__ inline i32x8 pad8(i32x4 v) {
  i32x8 r;
  r[0] = v[0]; r[1] = v[1]; r[2] = v[2]; r[3] = v[3];
  r[4] = 0; r[5] = 0; r[6] = 0; r[7] = 0;
  return r;
}

// ------------- Fused quantization: Hadamard(32) rotate + MXFP4 pack (x and w in one grid) ---
__global__ __launch_bounds__(256) void quant_fused(const float* __restrict__ x,
                                                   const float* __restrict__ wt,
                                                   unsigned char* __restrict__ xq,
                                                   unsigned char* __restrict__ xsc,
                                                   unsigned char* __restrict__ wq,
                                                   unsigned char* __restrict__ wsc,
                                                   const float* __restrict__ ags,
                                                   const float* __restrict__ wgs,
                                                   int xg, int Mrows, int Nrows, int kg) {
  const int first = blockIdx.x * 256;
  const bool isX = first < xg;
  const float* in        = isX ? x   : wt;
  unsigned char* outq    = isX ? xq  : wq;
  unsigned char* outsc   = isX ? xsc : wsc;
  const float gs         = isX ? ags[0] : wgs[0];
  const int rows         = isX ? Mrows : Nrows;
  const int base         = isX ? first : first - xg;
  const int g = base + threadIdx.x;
  const int r = g / kg, j = g - r * kg;

  float t[32];
  const float4* p4 = (const float4*)(in + (size_t)g * 32);
#pragma unroll
  for (int i = 0; i < 8; ++i) {
    float4 v4 = p4[i];
    t[4 * i + 0] = v4.x; t[4 * i + 1] = v4.y;
    t[4 * i + 2] = v4.z; t[4 * i + 3] = v4.w;
  }
#pragma unroll
  for (int s = 0; s < 5; ++s) {
    const int hh = 1 << s;
#pragma unroll
    for (int i = 0; i < 32; ++i) {
      if ((i & hh) == 0) {
        float a = t[i], b = t[i + hh];
        t[i] = a + b;
        t[i + hh] = a - b;
      }
    }
  }

  const float c = 0.17677669529663687f;  // 32^-0.5
  float v[32];
  float am = 0.0f;
#pragma unroll
  for (int i = 0; i < 32; ++i) {
    float vi = (t[i] * c) * gs;
    v[i] = vi;
    am = fmaxf(am, fabsf(vi));
  }

  float a6 = am / 6.0f;
  int ex;
  float mant = frexpf(a6, &ex);
  int e = (mant == 0.5f) ? ex - 1 : ex;  // exact ceil(log2(a6))
  if (e < -127) e = -127;
  if (e > 127) e = 127;
  float inv_s = ldexpf(1.0f, -e);

  unsigned int dw[4] = {0u, 0u, 0u, 0u};
#pragma unroll
  for (int i = 0; i < 32; ++i) {
    float u = v[i] * inv_s;
    float au = fabsf(u);
    int idx = (au > 0.25f) + (au > 0.75f) + (au > 1.25f) + (au > 1.75f)
            + (au > 2.5f) + (au > 3.5f) + (au > 5.0f);
    int code = idx | ((u < 0.0f) ? 8 : 0);
    dw[i >> 3] |= (unsigned)code << ((i & 7) * 4);
  }
  i32x4 packed;
  packed[0] = (int)dw[0]; packed[1] = (int)dw[1];
  packed[2] = (int)dw[2]; packed[3] = (int)dw[3];
  *(i32x4*)(outq + (size_t)r * ((size_t)kg * 16) + (size_t)j * 16) = packed;

  // scale byte: layout [superstep s(256k)][row][8B], byte p = h*4 + kk for block j0 = 2*kk + h
  int s = j >> 3, j0 = j & 7;
  int p = ((j0 & 1) << 2) | (j0 >> 1);
  if (kg == 128) {
    __shared__ unsigned char sl[256];  // [16 steps][2 rows][8B]
    sl[(s << 4) | ((r & 1) << 3) | p] = (unsigned char)(e + 127);
    __syncthreads();
    if (threadIdx.x < 64) {
      int si = threadIdx.x >> 2, wd = threadIdx.x & 3;
      unsigned int vv = *(const unsigned int*)&sl[(si << 4) | (wd << 2)];
      size_t r0 = (size_t)(base / 128);
      *(unsigned int*)(outsc + ((size_t)si * rows + r0) * 8 + (wd << 2)) = vv;
    }
  } else {
    outsc[((size_t)s * rows + r) * 8 + p] = (unsigned char)(e + 127);
  }
}

// ---------------- 128x128 MX-FP4 GEMM, BK=256, dbuf, ONE phase/tile, race-free ----------
// 4 waves (2M x 2N), 2 blocks/CU (LDS 68KB). Per tile: {16 ds_read + 4 scale reads ->
// lgkmcnt(0) -> barrier (ALL waves' reads drained before any wave proceeds) ->
// stage set(t+2) into the just-read buffer (safe: write-after-drained-read) ->
// 16 MFMA -> vmcnt(10) (drains set(t+1)) -> barrier}. Ledger: 10 VMEM/set; steady
// queue after stage = [set(t+1)^10, set(t+2)^10]. Swizzle: LDS(row,chunk) holds
// global (row, chunk^(row&7)); 16B chunks; reads at ((2kk+h)^(row&7))<<4 (R6-proven).

#define STAGE(mb, kt, hh, ldsHalf) do {                                              \
    const unsigned char* _s = (mb) + (size_t)((hh)*64 + (w << 3) + (l >> 3)) * KB2   \
                      + (size_t)(kt) * 128 + (size_t)csw * 16;                       \
    gload_lds16(_s, (unsigned char*)(ldsHalf) + (w << 10));                          \
    gload_lds16(_s + ((size_t)KB2 << 5), (unsigned char*)(ldsHalf) + (w << 10) + 4096); \
  } while (0)

#define STAGE_ASC(kt, bf) gload_lds4(AscG + ((size_t)(kt) * M + brow) * 8 + (tid << 2), \
                                     (unsigned char*)&asc[bf][0] + (w << 8))
#define STAGE_BSC(kt, bf) gload_lds4(BscG + ((size_t)(kt) * N + bcol) * 8 + (tid << 2), \
                                     (unsigned char*)&bsc[bf][0] + (w << 8))

// full tile set: 4 B-data + BSC + 4 A-data + ASC = 10 VMEM
#define STAGESET(kt, bf) do {                                                        \
    STAGE(Bb, kt, 0, &lds[bf][1][0]); STAGE(Bb, kt, 1, &lds[bf][1][8192]);           \
    STAGE_BSC(kt, bf);                                                               \
    STAGE(Ab, kt, 0, &lds[bf][0][0]); STAGE(Ab, kt, 1, &lds[bf][0][8192]);           \
    STAGE_ASC(kt, bf);                                                               \
  } while (0)

#define LOADB(bf) do {                                                               \
    const unsigned char* _bb = &lds[bf][1][0];                                       \
    _Pragma("unroll")                                                                \
    for (int nt = 0; nt < 2; ++nt) {                                                 \
      int row = wn * 64 + nt * 32 + (l & 31);                                        \
      int xr = row & 7;                                                              \
      _Pragma("unroll")                                                              \
      for (int kk = 0; kk < 4; ++kk)                                                 \
        bfr[nt][kk] = *(const i32x4*)(_bb + row * 128 + (((kk * 2 + h) ^ xr) << 4)); \
      sb[nt] = *(const int*)((const unsigned char*)&bsc[bf][0] + row * 8 + h * 4);   \
    } } while (0)

#define LOADA(bf) do {                                                               \
    const unsigned char* _ab = &lds[bf][0][0];                                       \
    _Pragma("unroll")                                                                \
    for (int mt = 0; mt < 2; ++mt) {                                                 \
      int row = wm * 64 + mt * 32 + (l & 31);                                        \
      int xr = row & 7;                                                              \
      _Pragma("unroll")                                                              \
      for (int kk = 0; kk < 4; ++kk)                                                 \
        af[mt][kk] = *(const i32x4*)(_ab + row * 128 + (((kk * 2 + h) ^ xr) << 4));  \
      sa[mt] = *(const int*)((const unsigned char*)&asc[bf][0] + row * 8 + h * 4);   \
    } } while (0)

#define MF1(mt, nt, kk)                                                              \
  acc[mt][nt] = __builtin_amdgcn_mfma_scale_f32_32x32x64_f8f6f4(                     \
      pad8(af[mt][kk]), pad8(bfr[nt][kk]), acc[mt][nt], 4, 4, kk, sa[mt], kk, sb[nt]);

#define MFMAQ16() do {                                                               \
    __builtin_amdgcn_s_setprio(1);                                                   \
    MF1(0, 0, 0) MF1(0, 1, 0) MF1(1, 0, 0) MF1(1, 1, 0)                              \
    MF1(0, 0, 1) MF1(0, 1, 1) MF1(1, 0, 1) MF1(1, 1, 1)                              \
    MF1(0, 0, 2) MF1(0, 1, 2) MF1(1, 0, 2) MF1(1, 1, 2)                              \
    MF1(0, 0, 3) MF1(0, 1, 3) MF1(1, 0, 3) MF1(1, 1, 3)                              \
    __builtin_amdgcn_s_setprio(0);                                                   \
  } while (0)

#define DRAIN_THEN_BAR() do {                                                        \
    asm volatile("s_waitcnt lgkmcnt(0)" ::: "memory");                               \
    __builtin_amdgcn_sched_barrier(0);                                               \
    __builtin_amdgcn_s_barrier();                                                    \
  } while (0)

#define ENDP() __builtin_amdgcn_s_barrier()
#define VM10() asm volatile("s_waitcnt vmcnt(10)" ::: "memory")

__global__ __launch_bounds__(256, 2) void gemm128_fp4(const unsigned char* __restrict__ Aq,
                                                      const unsigned char* __restrict__ Bq,
                                                      const unsigned char* __restrict__ AscG,
                                                      const unsigned char* __restrict__ BscG,
                                                      float* __restrict__ C,
                                                      const float* __restrict__ bias,
                                                      const float* __restrict__ gsx,
                                                      const float* __restrict__ gsw,
                                                      int M, int N, int K) {
  __shared__ __align__(16) unsigned char lds[2][2][16384];  // [buf][A/B][128 rows x 128B]
  __shared__ __align__(16) unsigned char asc[2][1024];      // [buf][128 rows x 8B]
  __shared__ __align__(16) unsigned char bsc[2][1024];

  const int tid = threadIdx.x;
  const int w = tid >> 6, l = tid & 63;
  const int wm = w >> 1, wn = w & 1;
  const int h = l >> 5;
  const int csw = (l & 7) ^ (l >> 3);  // inverse-swizzled source chunk (row&7 == l>>3)
  const int KB2 = K >> 1;              // bytes per row

  // T1 + L2 supertiling (proven: FETCH 148->70MB): XCD band + 8x8 supertiles.
  const int ntn = N >> 7;
  const int nwg = gridDim.x;
  int r_t, c_t;
  {
    int bid = blockIdx.x;
    if ((nwg & 7) == 0) {
      int x = bid & 7, o = bid >> 3, cpx = nwg >> 3;
      int rpx = cpx / ntn;
      if ((ntn & 7) == 0 && rpx > 0 && (cpx % ntn) == 0) {
        int g8 = o & 7, rr = (o >> 3) % rpx, ss = o / (8 * rpx);
        r_t = x * rpx + rr;
        c_t = ss * 8 + g8;
      } else {
        int lin = x * cpx + o;
        r_t = lin / ntn; c_t = lin % ntn;
      }
    } else {
      r_t = bid / ntn; c_t = bid % ntn;
    }
  }
  const size_t brow = (size_t)r_t * 128;
  const size_t bcol = (size_t)c_t * 128;

  const unsigned char* Ab = Aq + brow * (size_t)KB2;
  const unsigned char* Bb = Bq + bcol * (size_t)KB2;

  f32x16 acc[2][2];
#pragma unroll
  for (int m = 0; m < 2; ++m)
#pragma unroll
    for (int n = 0; n < 2; ++n)
#pragma unroll
      for (int r = 0; r < 16; ++r) acc[m][n][r] = 0.0f;

  i32x4 af[2][4], bfr[2][4];
  int sa[2], sb[2];

  const int nkt = K / 256;       // 16 tiles; scale superstep index == tile index

  // Prologue: set(0)->buf0 (10), set(1)->buf1 (10); VM10 drains set0, keeps set1.
  STAGESET(0, 0);
  STAGESET(1, 1);
  VM10();
  __builtin_amdgcn_s_barrier();

  for (int t = 0; t < nkt; ++t) {
    const int p = t & 1;
    const int t2 = (t + 2 < nkt) ? t + 2 : nkt - 1;  // tail: stages a buffer never read again

    LOADB(p); LOADA(p);          // 16 ds_read_b128 + 4 ds_read_b32 into regs
    DRAIN_THEN_BAR();            // all waves' reads of buf[p] complete before anyone stages
    STAGESET(t2, p);             // overwrite buf[p] (readers provably done)
    __builtin_amdgcn_sched_barrier(0);
    MFMAQ16();                   // compute on registers while DMA flies
    VM10();                      // drains set(t+1) (next tile's data); keeps set(t+2)
    ENDP();                      // collective: every wave's set(t+1) slice landed
  }

  const float inv = 1.0f / (gsx[0] * gsw[0]);
#pragma unroll
  for (int nt = 0; nt < 2; ++nt) {
    const int col = (int)bcol + wn * 64 + nt * 32 + (l & 31);
    const float bv = bias[col];
#pragma unroll
    for (int mt = 0; mt < 2; ++mt) {
      const size_t rbase = brow + (size_t)(wm * 64 + mt * 32 + 4 * h);
#pragma unroll
      for (int r = 0; r < 16; ++r) {
        const size_t row = rbase + (r & 3) + 8 * (r >> 2);
        C[row * (size_t)N + col] = acc[mt][nt][r] * inv + bv;
      }
    }
  }
}

extern "C" void kernel_launch(void* const* d_in, const int* in_sizes, int n_in,
                              void* d_out, int out_size, void* d_ws, size_t ws_size,
                              hipStream_t stream) {
  const float* x    = (const float*)d_in[0];
  const float* wgt  = (const float*)d_in[1];
  const float* bias = (const float*)d_in[2];
  const float* wgs  = (const float*)d_in[4];
  const float* ags  = (const float*)d_in[5];

  const int N = in_sizes[2];            // 4096
  const int K = in_sizes[1] / N;        // 4096
  const int M = in_sizes[0] / K;        // 8192
  const int kg = K / 32;                // 128

  unsigned char* aq  = (unsigned char*)d_ws;
  unsigned char* bq  = aq + (size_t)M * (K / 2);
  unsigned char* asc = bq + (size_t)N * (K / 2);
  unsigned char* bsc = asc + (size_t)M * kg;

  const int xg = in_sizes[0] / 32;
  const int wg = in_sizes[1] / 32;
  quant_fused<<<dim3((xg + wg) / 256), dim3(256), 0, stream>>>(
      x, wgt, aq, asc, bq, bsc, ags, wgs, xg, M, N, kg);

  dim3 grid((M / 128) * (N / 128));
  gemm128_fp4<<<grid, dim3(256), 0, stream>>>(aq, bq, asc, bsc, (float*)d_out, bias,
                                              ags, wgs, M, N, K);
}